// Round 5
// baseline (183.768 us; speedup 1.0000x reference)
//
#include <hip/hip_runtime.h>
#include <math.h>

// ---------------------------------------------------------------------------
// QuantumGenerator, register-resident recompute version (R4 + grid fix).
// R4 crashed: 2048 blocks staged 4x the actual z extent (2 batches/block =
// 2048 float4s/block; 1024 batches need 512 blocks, not 2048) -> OOB page
// fault. All other indexing verified in-bounds.
// Structure: one lane owns 64 consecutive floats of one batch; all 4 qcnn
// layers are then lane-local (L1: 4 chans; L2: 1 chan; L3: 4 rows; L4: 2 rows).
// BN -> 4 recompute passes from LLC-hot z, plain per-batch partial stores
// (no global atomics - R3 regression), tiny stats kernels between passes.
// ---------------------------------------------------------------------------

__global__ __launch_bounds__(256) void build_V_kernel(
    const float* __restrict__ w1, const float* __restrict__ w2,
    const float* __restrict__ w3, const float* __restrict__ w4,
    float* __restrict__ V)
{
    int t = blockIdx.x * blockDim.x + threadIdx.x;
    if (t >= 340) return;
    const float* w; float* vout;
    if (t < 256)      { w = w1 + t*18;        vout = V + t*16; }
    else if (t < 320) { w = w2 + (t-256)*18;  vout = V + 4096 + (t-256)*16; }
    else if (t < 336) { w = w3 + (t-320)*18;  vout = V + 5120 + (t-320)*16; }
    else              { w = w4 + (t-336)*18;  vout = V + 5376 + (t-336)*16; }
    const int perm[8] = {0,5,7,2,3,6,4,1};   // CNOT ring row permutation
    float U[8][8];
    #pragma unroll
    for (int i=0;i<8;i++)
        #pragma unroll
        for (int jj=0;jj<8;jj++) U[i][jj] = (i==jj) ? 1.0f : 0.0f;
    for (int l=0;l<6;l++){
        float c0 = cosf(0.5f*w[l*3+0]), s0 = sinf(0.5f*w[l*3+0]);
        float c1 = cosf(0.5f*w[l*3+1]), s1 = sinf(0.5f*w[l*3+1]);
        float c2 = cosf(0.5f*w[l*3+2]), s2 = sinf(0.5f*w[l*3+2]);
        #pragma unroll
        for (int col=0; col<8; col++){
            float v[8];
            #pragma unroll
            for (int r=0;r<8;r++) v[r] = U[r][col];
            #pragma unroll
            for (int bb=0;bb<8;bb+=2){ float x=v[bb], y=v[bb+1]; v[bb]=c2*x-s2*y; v[bb+1]=s2*x+c2*y; }
            #pragma unroll
            for (int g=0;g<8;g+=4)
                #pragma unroll
                for (int i=0;i<2;i++){ int a=g+i, bq=g+i+2; float x=v[a], y=v[bq]; v[a]=c1*x-s1*y; v[bq]=s1*x+c1*y; }
            #pragma unroll
            for (int i=0;i<4;i++){ float x=v[i], y=v[i+4]; v[i]=c0*x-s0*y; v[i+4]=s0*x+c0*y; }
            #pragma unroll
            for (int r=0;r<8;r++) U[perm[r]][col] = v[r];
        }
    }
    #pragma unroll
    for (int jj=0;jj<4;jj++)
        #pragma unroll
        for (int k=0;k<4;k++) vout[jj*4+k] = U[jj][k];
}

__device__ __forceinline__ void qstep(
    float x0, float x1, float x2, float x3,
    float4 v0, float4 v1, float4 v2, float4 v3, float* o)
{
    float nrm = sqrtf(x0*x0 + x1*x1 + x2*x2 + x3*x3);
    float inv = 1.0f / fmaxf(nrm, 1e-9f);
    float a0=x0*inv, a1=x1*inv, a2=x2*inv, a3=x3*inv;
    float q0 = v0.x*a0 + v0.y*a1 + v0.z*a2 + v0.w*a3;
    float q1 = v1.x*a0 + v1.y*a1 + v1.z*a2 + v1.w*a3;
    float q2 = v2.x*a0 + v2.y*a1 + v2.z*a2 + v2.w*a3;
    float q3 = v3.x*a0 + v3.y*a1 + v3.z*a2 + v3.w*a3;
    q0*=q0; q1*=q1; q2*=q2; q3*=q3;
    float dinv = 1.0f / fmaxf(q0+q1+q2+q3, 1e-9f);
    o[0]=q0*dinv; o[1]=q1*dinv; o[2]=q2*dinv; o[3]=q3*dinv;
}

// One lane owns 64 consecutive floats of one batch; block = 128 thr = 2
// batches = 2048 float4s staged.  GRID MUST BE 512 (1024 batches / 2).
template<int NL, bool WS4>
__global__ __launch_bounds__(128) void pass_kernel(
    const float* __restrict__ z, const float* __restrict__ V,
    const float* __restrict__ sc2, const float* __restrict__ sh2,
    const float* __restrict__ sc3, const float* __restrict__ sh3,
    const float* __restrict__ sc4, const float* __restrict__ sh4,
    float* __restrict__ part, float* __restrict__ s4out)
{
    __shared__ __align__(16) float4 lds[2048];   // 32 KB: 2 batches
    const int tid   = threadIdx.x;
    const int batch = blockIdx.x*2 + (tid>>6);
    const int L     = tid & 63;                  // lane-in-batch = chunk owner

    // stage-in: coalesced global float4 -> XOR-swizzled LDS
    const float4* z4 = reinterpret_cast<const float4*>(z) + (size_t)blockIdx.x*2048;
    #pragma unroll
    for (int k=0;k<16;k++){
        int G = k*128 + tid;
        lds[(G & ~15) | ((G & 15) ^ ((G >> 4) & 7))] = z4[G];
    }
    __syncthreads();

    float d[64];
    #pragma unroll
    for (int f=0; f<16; f++){
        float4 v = lds[tid*16 + (f ^ (tid & 7))];
        d[4*f+0]=v.x; d[4*f+1]=v.y; d[4*f+2]=v.z; d[4*f+3]=v.w;
    }

    // ---- L1: 4 channels of 16 floats (4x4), fully lane-local ----
    #pragma unroll
    for (int j=0;j<4;j++){
        const float4* Vc = reinterpret_cast<const float4*>(V) + (size_t)(L*4+j)*4;
        float4 v0=Vc[0], v1=Vc[1], v2=Vc[2], v3=Vc[3];
        float t[16];
        #pragma unroll
        for (int p=0;p<4;p++){
            int oh=p>>1, ow=p&1;
            int base = j*16 + oh*8 + ow*2;
            qstep(d[base], d[base+1], d[base+4], d[base+5], v0,v1,v2,v3, &t[p*4]);
        }
        #pragma unroll
        for (int i=0;i<16;i++) d[j*16+i] = t[i];
    }
    if constexpr (NL==1){
        float s=0.0f, q=0.0f;
        #pragma unroll
        for (int i=0;i<64;i++){ s += d[i]; q += d[i]*d[i]; }
        part[batch*128 + L*2    ] = s;    // BN-channel of s1 == L
        part[batch*128 + L*2 + 1] = q;
        return;
    }

    if constexpr (NL>=2){
        // ---- BN2+relu (channel == L), then L2: one 64-float channel (8x8) ----
        { float sc = sc2[L], sh = sh2[L];
          #pragma unroll
          for (int i=0;i<64;i++) d[i] = fmaxf(fmaf(d[i],sc,sh), 0.0f); }
        {
            const float4* Vc = reinterpret_cast<const float4*>(V + 4096) + (size_t)L*4;
            float4 v0=Vc[0], v1=Vc[1], v2=Vc[2], v3=Vc[3];
            #pragma unroll
            for (int oh=0;oh<4;oh++){
                float t[16];
                #pragma unroll
                for (int ow=0;ow<4;ow++){
                    int base = oh*16 + ow*2;
                    qstep(d[base], d[base+1], d[base+8], d[base+9], v0,v1,v2,v3, &t[ow*4]);
                }
                #pragma unroll
                for (int i=0;i<16;i++) d[oh*16+i] = t[i];
            }
        }
        if constexpr (NL==2){
            float s=0.0f, q=0.0f;
            #pragma unroll
            for (int i=0;i<64;i++){ s += d[i]; q += d[i]*d[i]; }
            s += __shfl_xor(s,1); q += __shfl_xor(q,1);
            s += __shfl_xor(s,2); q += __shfl_xor(q,2);
            if ((L&3)==0){
                int oc = L>>2;                    // 16 BN-channels, 4 lanes each
                part[batch*32 + oc*2    ] = s;
                part[batch*32 + oc*2 + 1] = q;
            }
            return;
        }
    }

    if constexpr (NL>=3){
        // ---- BN3+relu (channel == L>>2), then L3: 4 rows of a 16x16 channel ----
        { float sc = sc3[L>>2], sh = sh3[L>>2];
          #pragma unroll
          for (int i=0;i<64;i++) d[i] = fmaxf(fmaf(d[i],sc,sh), 0.0f); }
        {
            const int c3 = L>>2;
            const float4* Vc = reinterpret_cast<const float4*>(V + 5120) + (size_t)c3*4;
            float4 v0=Vc[0], v1=Vc[1], v2=Vc[2], v3=Vc[3];
            #pragma unroll
            for (int s5=0;s5<2;s5++){            // two 32-float strips (row-pairs)
                float t[32];
                #pragma unroll
                for (int ow=0;ow<8;ow++){
                    int base = s5*32 + ow*2;
                    qstep(d[base], d[base+1], d[base+16], d[base+17], v0,v1,v2,v3, &t[ow*4]);
                }
                #pragma unroll
                for (int i=0;i<32;i++) d[s5*32+i] = t[i];
            }
        }
        if constexpr (NL==3){
            float s=0.0f, q=0.0f;
            #pragma unroll
            for (int i=0;i<64;i++){ s += d[i]; q += d[i]*d[i]; }
            #pragma unroll
            for (int off=1; off<16; off<<=1){ s += __shfl_xor(s,off); q += __shfl_xor(q,off); }
            if ((L&15)==0){
                int oc = L>>4;                    // 4 BN-channels, 16 lanes each
                part[batch*8 + oc*2    ] = s;
                part[batch*8 + oc*2 + 1] = q;
            }
            return;
        }
    }

    if constexpr (NL>=4){
        // ---- BN4+relu (channel == L>>4), then L4: 2 rows of a 32x32 channel ----
        { float sc = sc4[L>>4], sh = sh4[L>>4];
          #pragma unroll
          for (int i=0;i<64;i++) d[i] = fmaxf(fmaf(d[i],sc,sh), 0.0f); }
        {
            const int c4 = L>>4;
            const float4* Vc = reinterpret_cast<const float4*>(V + 5376) + (size_t)c4*4;
            float4 v0=Vc[0], v1=Vc[1], v2=Vc[2], v3=Vc[3];
            float t[32];
            #pragma unroll
            for (int i=0;i<32;i++) t[i] = d[32+i];        // save row 2oh+1
            #pragma unroll
            for (int ow=15; ow>=0; ow--){                 // descending: write-safe
                qstep(d[2*ow], d[2*ow+1], t[2*ow], t[2*ow+1], v0,v1,v2,v3, &d[4*ow]);
            }
        }
        // stats of s4 (single BN channel)
        {
            float s=0.0f, q=0.0f;
            #pragma unroll
            for (int i=0;i<64;i++){ s += d[i]; q += d[i]*d[i]; }
            #pragma unroll
            for (int off=1; off<64; off<<=1){ s += __shfl_xor(s,off); q += __shfl_xor(q,off); }
            if (L==0){
                part[batch*2    ] = s;
                part[batch*2 + 1] = q;
            }
        }
        if constexpr (WS4){
            __syncthreads();                              // lds reuse
            #pragma unroll
            for (int f=0;f<16;f++)
                lds[tid*16 + (f ^ (tid & 7))] =
                    make_float4(d[4*f], d[4*f+1], d[4*f+2], d[4*f+3]);
            __syncthreads();
            float4* o4 = reinterpret_cast<float4*>(s4out) + (size_t)blockIdx.x*2048;
            #pragma unroll
            for (int k=0;k<16;k++){
                int G = k*128 + tid;
                o4[G] = lds[(G & ~15) | ((G & 15) ^ ((G >> 4) & 7))];
            }
        }
    }
}

// Reduce part[1024][2*OC] over batches -> scale/shift (gamma/beta folded).
__global__ __launch_bounds__(256) void stats_kernel(
    const float* __restrict__ part, int OC,
    const float* __restrict__ gamma, const float* __restrict__ beta,
    float invN, float* __restrict__ scale, float* __restrict__ shift)
{
    __shared__ float sh8[8];
    int oc = blockIdx.x;
    float s=0.0f, q=0.0f;
    for (int b=threadIdx.x; b<1024; b+=256){
        s += part[b*2*OC + oc*2    ];
        q += part[b*2*OC + oc*2 + 1];
    }
    #pragma unroll
    for (int off=32; off; off>>=1){ s += __shfl_down(s,off); q += __shfl_down(q,off); }
    int wid = threadIdx.x >> 6, lane = threadIdx.x & 63;
    if (lane==0){ sh8[wid]=s; sh8[4+wid]=q; }
    __syncthreads();
    if (threadIdx.x==0){
        s = sh8[0]+sh8[1]+sh8[2]+sh8[3];
        q = sh8[4]+sh8[5]+sh8[6]+sh8[7];
        float mean = s*invN;
        float var  = q*invN - mean*mean;
        float r    = 1.0f / sqrtf(var + 1e-5f);
        float sc   = gamma[oc]*r;
        scale[oc] = sc;
        shift[oc] = beta[oc] - mean*sc;
    }
}

__device__ __forceinline__ float fast_tanh(float x){
    float e = __expf(2.0f*x);          // inf/0 endpoints give +/-1 correctly
    return 1.0f - 2.0f/(e + 1.0f);
}

__global__ __launch_bounds__(256) void final_kernel(
    const float* __restrict__ s4, const float* __restrict__ scf,
    const float* __restrict__ shf, float* __restrict__ out_tanh,
    float* __restrict__ out_bn)
{
    float sc = scf[0], sh = shf[0];
    int i = blockIdx.x*blockDim.x + threadIdx.x;   // 1M float4s
    float4 v = reinterpret_cast<const float4*>(s4)[i];
    float4 bn = make_float4(fmaf(v.x,sc,sh), fmaf(v.y,sc,sh),
                            fmaf(v.z,sc,sh), fmaf(v.w,sc,sh));
    reinterpret_cast<float4*>(out_bn)[i] = bn;
    reinterpret_cast<float4*>(out_tanh)[i] =
        make_float4(fast_tanh(bn.x), fast_tanh(bn.y),
                    fast_tanh(bn.z), fast_tanh(bn.w));
}

extern "C" void kernel_launch(void* const* d_in, const int* in_sizes, int n_in,
                              void* d_out, int out_size, void* d_ws, size_t ws_size,
                              hipStream_t stream)
{
    const float* z      = (const float*)d_in[0];
    const float* w1     = (const float*)d_in[1];
    const float* w2     = (const float*)d_in[2];
    const float* w3     = (const float*)d_in[3];
    const float* w4     = (const float*)d_in[4];
    const float* gamma2 = (const float*)d_in[5];
    const float* beta2  = (const float*)d_in[6];
    const float* gamma3 = (const float*)d_in[7];
    const float* beta3  = (const float*)d_in[8];
    const float* gamma4 = (const float*)d_in[9];
    const float* beta4  = (const float*)d_in[10];
    const float* gammaf = (const float*)d_in[11];
    const float* betaf  = (const float*)d_in[12];
    float* out = (float*)d_out;
    float* ws  = (float*)d_ws;

    float* V     = ws;            // 5440 floats
    float* sc2   = ws + 6144;  float* sh2 = ws + 6208;   // 64 each
    float* sc3   = ws + 6272;  float* sh3 = ws + 6336;   // 16 each
    float* sc4   = ws + 6400;  float* sh4 = ws + 6464;   // 4 each
    float* scf   = ws + 6528;  float* shf = ws + 6592;   // 1 each
    float* part1 = ws + 8192;                            // 1024*128
    float* part2 = part1 + 131072;                       // 1024*32
    float* part3 = part2 + 32768;                        // 1024*8
    float* part4 = part3 + 8192;                         // 1024*2

    float* out_tanh = out;                  // output 0
    float* s4       = out + 4194304;        // output 1 (written by P4)
    float* out_bn   = out + 8388608;        // output 2

    build_V_kernel<<<2, 256, 0, stream>>>(w1, w2, w3, w4, V);

    pass_kernel<1,false><<<512, 128, 0, stream>>>(
        z, V, nullptr,nullptr, nullptr,nullptr, nullptr,nullptr, part1, nullptr);
    stats_kernel<<<64, 256, 0, stream>>>(part1, 64, gamma2, beta2,
        1.0f/65536.0f, sc2, sh2);

    pass_kernel<2,false><<<512, 128, 0, stream>>>(
        z, V, sc2,sh2, nullptr,nullptr, nullptr,nullptr, part2, nullptr);
    stats_kernel<<<16, 256, 0, stream>>>(part2, 16, gamma3, beta3,
        1.0f/262144.0f, sc3, sh3);

    pass_kernel<3,false><<<512, 128, 0, stream>>>(
        z, V, sc2,sh2, sc3,sh3, nullptr,nullptr, part3, nullptr);
    stats_kernel<<<4, 256, 0, stream>>>(part3, 4, gamma4, beta4,
        1.0f/1048576.0f, sc4, sh4);

    pass_kernel<4,true><<<512, 128, 0, stream>>>(
        z, V, sc2,sh2, sc3,sh3, sc4,sh4, part4, s4);
    stats_kernel<<<1, 256, 0, stream>>>(part4, 1, gammaf, betaf,
        1.0f/4194304.0f, scf, shf);

    final_kernel<<<4096, 256, 0, stream>>>(s4, scf, shf, out_tanh, out_bn);
}